// Round 6
// baseline (308.339 us; speedup 1.0000x reference)
//
#include <hip/hip_runtime.h>
#include <hip/hip_bf16.h>

using u16 = unsigned short;
using u32 = unsigned int;

typedef __bf16 bf16x8 __attribute__((ext_vector_type(8)));
typedef float f32x4 __attribute__((ext_vector_type(4)));

__device__ __forceinline__ u16 f2bf(float f) {
  union { float f; u32 u; } c; c.f = f;
  u32 u = c.u;
  u32 r = u + 0x7fffu + ((u >> 16) & 1u);   // RNE
  return (u16)(r >> 16);
}
__device__ __forceinline__ u32 pack2(float a, float b) {
  return (u32)f2bf(a) | ((u32)f2bf(b) << 16);
}

constexpr int Bb  = 64;    // graphs
constexpr int L   = 1024;  // nodes/graph
constexpr int IN  = 128;
constexpr int OUT = 128;
constexpr int FLR = 64;
constexpr int N   = Bb * L;

// ---------------------------------------------------------------------------
// k_pack: one-time weight repack into MFMA B-fragment order (bf16). UNCHANGED.
// ---------------------------------------------------------------------------
__global__ __launch_bounds__(256) void k_pack(
    const float* __restrict__ Wout, const float* __restrict__ Wh,
    u16* __restrict__ Bp, u16* __restrict__ Whp)
{
  const int blk = blockIdx.x;
  if (blk < 16) {
    int t2 = blk * 256 + threadIdx.x;    // 0..4095 frag-lanes
    int lane = t2 & 63, kstep = (t2 >> 6) & 7, ntile = t2 >> 9;
    int n  = ntile * 16 + (lane & 15);
    int kb = kstep * 32 + (lane >> 4) * 8;
    u16* dst = Bp + (size_t)t2 * 8;
#pragma unroll
    for (int j = 0; j < 8; ++j) dst[j] = f2bf(Wout[(kb + j) * OUT + n]);
  } else {
#pragma unroll
    for (int i = 0; i < 4; ++i) {
      int t2 = i * 256 + threadIdx.x;    // 0..1023 frag-lanes
      int l = t2 & 63, ks = (t2 >> 6) & 3, nt = t2 >> 8;
      int kb = ks * 32 + (l >> 4) * 8;
      u16* dst = Whp + (size_t)t2 * 8;
#pragma unroll
      for (int j = 0; j < 8; ++j)
        dst[j] = f2bf(Wh[(size_t)(kb + j) * FLR + nt * 16 + (l & 15)]);
    }
  }
}

// ---------------------------------------------------------------------------
// k_sh: UNCHANGED from round 5.
// ---------------------------------------------------------------------------
__global__ __launch_bounds__(256) void k_sh(
    const float* __restrict__ x, const float* __restrict__ Ws, const float* __restrict__ bs,
    const u16* __restrict__ Whp, const float* __restrict__ bh,
    float* __restrict__ s_buf, u16* __restrict__ h_buf, u16* __restrict__ xbf)
{
  __shared__ alignas(16) u16 whl[128 * 64];   // 16 KB: Wh bf16 frags

  const int tid = threadIdx.x;
  {
    const uint4* __restrict__ src = (const uint4*)Whp;
    uint4* dstl = (uint4*)whl;
#pragma unroll
    for (int i = 0; i < 4; ++i) {
      int idx = i * 256 + tid;
      dstl[idx] = src[idx];
    }
  }

  const int blk = blockIdx.x;
  const int lane = tid & 63;
  const int w = __builtin_amdgcn_readfirstlane(tid >> 6);
  const int mb = blk * 64 + w * 16;        // m-tile base node
  const int col = lane & 15;
  const int kq  = lane >> 4;               // 0..3
  const int mrow = mb + col;               // this lane's A row

  const float* xr = x + (size_t)mrow * IN;

  float sp0 = 0.f, sp1 = 0.f, sp2 = 0.f, sp3 = 0.f;
  bf16x8 a[4];
#pragma unroll
  for (int ks = 0; ks < 4; ++ks) {
    float4 xa = *(const float4*)(xr + ks * 32 + kq * 8);
    float4 xb = *(const float4*)(xr + ks * 32 + kq * 8 + 4);
    float xf[8] = {xa.x, xa.y, xa.z, xa.w, xb.x, xb.y, xb.z, xb.w};
#pragma unroll
    for (int j = 0; j < 8; ++j) {
      const float4 wsr = *(const float4*)(Ws + (size_t)(ks * 32 + kq * 8 + j) * 4);
      sp0 = fmaf(xf[j], wsr.x, sp0);
      sp1 = fmaf(xf[j], wsr.y, sp1);
      sp2 = fmaf(xf[j], wsr.z, sp2);
      sp3 = fmaf(xf[j], wsr.w, sp3);
    }
    union { __hip_bfloat162 h2[4]; bf16x8 v; } cv;
    cv.h2[0] = __float22bfloat162_rn(float2{xf[0], xf[1]});
    cv.h2[1] = __float22bfloat162_rn(float2{xf[2], xf[3]});
    cv.h2[2] = __float22bfloat162_rn(float2{xf[4], xf[5]});
    cv.h2[3] = __float22bfloat162_rn(float2{xf[6], xf[7]});
    a[ks] = cv.v;
  }

  if (xbf) {
#pragma unroll
    for (int ks = 0; ks < 4; ++ks)
      *(bf16x8*)(xbf + (((size_t)(blk * 4 + w) * 4 + ks) * 64 + lane) * 8) = a[ks];
  }

  sp0 += __shfl_xor(sp0, 16, 64); sp0 += __shfl_xor(sp0, 32, 64);
  sp1 += __shfl_xor(sp1, 16, 64); sp1 += __shfl_xor(sp1, 32, 64);
  sp2 += __shfl_xor(sp2, 16, 64); sp2 += __shfl_xor(sp2, 32, 64);
  sp3 += __shfl_xor(sp3, 16, 64); sp3 += __shfl_xor(sp3, 32, 64);
  if (kq == 0) {
    float4 sv;
    sv.x = sp0 + bs[0]; sv.y = sp1 + bs[1];
    sv.z = sp2 + bs[2]; sv.w = sp3 + bs[3];
    *(float4*)(s_buf + (size_t)mrow * 4) = sv;
  }

  __syncthreads();   // whl ready

  f32x4 acc[4];
#pragma unroll
  for (int nt = 0; nt < 4; ++nt) acc[nt] = f32x4{0.f, 0.f, 0.f, 0.f};

  const bf16x8* __restrict__ wf = (const bf16x8*)whl;
#pragma unroll
  for (int nt = 0; nt < 4; ++nt) {
#pragma unroll
    for (int ks = 0; ks < 4; ++ks) {
      acc[nt] = __builtin_amdgcn_mfma_f32_16x16x32_bf16(
          a[ks], wf[(nt * 4 + ks) * 64 + lane], acc[nt], 0, 0, 0);
    }
  }

#pragma unroll
  for (int nt = 0; nt < 4; ++nt) {
    float bias = bh[nt * 16 + col];
#pragma unroll
    for (int r = 0; r < 4; ++r) {
      float v = acc[nt][r] + bias;
      h_buf[(size_t)(mb + kq * 4 + r) * FLR + nt * 16 + col] = f2bf(v);
    }
  }
}

// ---------------------------------------------------------------------------
// k_fused: UNCHANGED from round 5 (the passing 68 µs version).
// ---------------------------------------------------------------------------
__global__ __launch_bounds__(512) void k_fused(
    const float* __restrict__ s_buf, const u16* __restrict__ h_buf,
    const float* __restrict__ x, const u16* __restrict__ Bp,
    const u16* __restrict__ xbf,
    const float* __restrict__ bout, float* __restrict__ out)
{
  __shared__ alignas(16) float lists[8 * 64 * 17];   // 8704 floats (34816 B)
  __shared__ float fk[64 * 17];                      // final 16 keys per node
  u16* agg_lds = (u16*)lists;          // [64][136] bf16, bytes [0, 17408)
  float* wk = lists + 4608;            // [64*17] f32 weights, floats [4608, 5696)

  const int lane = threadIdx.x & 63;
  const int w = __builtin_amdgcn_readfirstlane(threadIdx.x >> 6);
  const int g = blockIdx.y;
  const int nb0 = blockIdx.x * 64;
  const int node = g * L + nb0 + lane;

  const float4 si = *(const float4*)(s_buf + (size_t)node * 4);
  const float4* __restrict__ sg = (const float4*)(s_buf + (size_t)g * L * 4);
  const int jb = __builtin_amdgcn_readfirstlane(w * 128);

  float b[16];
#pragma unroll
  for (int k = 0; k < 16; ++k) b[k] = 3.0e38f;

#pragma unroll 4
  for (int j = 0; j < 128; ++j) {
    float4 sj = sg[jb + j];
    float dx = si.x - sj.x, dy = si.y - sj.y;
    float dz = si.z - sj.z, dw2 = si.w - sj.w;
    float d2 = fmaf(dw2, dw2, fmaf(dz, dz, fmaf(dy, dy, dx * dx)));
    u32 db = __float_as_uint(d2);
    float key = __uint_as_float((db & 0xFFFFFC00u) | (u32)(jb + j));
#pragma unroll
    for (int k = 15; k >= 1; --k) b[k] = __builtin_amdgcn_fmed3f(key, b[k - 1], b[k]);
    b[0] = fminf(key, b[0]);
  }

#pragma unroll
  for (int k = 0; k < 16; ++k) lists[(w * 64 + lane) * 17 + k] = b[k];
  __syncthreads();

  float c[16];
  if (w < 4) {
#pragma unroll
    for (int i = 0; i < 16; ++i)
      c[i] = fminf(b[i], lists[((w + 4) * 64 + lane) * 17 + (15 - i)]);
#pragma unroll
    for (int dd = 8; dd >= 1; dd >>= 1) {
#pragma unroll
      for (int i = 0; i < 16; ++i) {
        if ((i & dd) == 0) {
          float lo = fminf(c[i], c[i | dd]);
          float hi = fmaxf(c[i], c[i | dd]);
          c[i] = lo; c[i | dd] = hi;
        }
      }
    }
#pragma unroll
    for (int k = 0; k < 16; ++k) lists[(w * 64 + lane) * 17 + k] = c[k];
  }
  __syncthreads();
  if (w < 2) {
#pragma unroll
    for (int i = 0; i < 16; ++i)
      c[i] = fminf(c[i], lists[((w + 2) * 64 + lane) * 17 + (15 - i)]);
#pragma unroll
    for (int dd = 8; dd >= 1; dd >>= 1) {
#pragma unroll
      for (int i = 0; i < 16; ++i) {
        if ((i & dd) == 0) {
          float lo = fminf(c[i], c[i | dd]);
          float hi = fmaxf(c[i], c[i | dd]);
          c[i] = lo; c[i | dd] = hi;
        }
      }
    }
#pragma unroll
    for (int k = 0; k < 16; ++k) lists[(w * 64 + lane) * 17 + k] = c[k];
  }
  __syncthreads();
  if (w == 0) {
#pragma unroll
    for (int i = 0; i < 16; ++i) {
      float o = lists[(64 + lane) * 17 + (15 - i)];
      float kf = fminf(c[i], o);
      fk[lane * 17 + i] = kf;
      wk[lane * 17 + i] =
          __expf(-10.0f * __uint_as_float(__float_as_uint(kf) & 0xFFFFFC00u));
    }
  }
  __syncthreads();        // fk/wk ready; lists[] selection data dead

  {
    const int q     = lane & 7;              // dim chunk (8 bf16 = 16 B)
    const int nodeL = w * 8 + (lane >> 3);   // 0..63
    const u16* __restrict__ hg = h_buf + (size_t)g * L * FLR;

    float m[8], xx[8];
#pragma unroll
    for (int j = 0; j < 8; ++j) { m[j] = 0.f; xx[j] = -3.0e38f; }

#pragma unroll 4
    for (int k = 0; k < 16; ++k) {
      u32 u    = __float_as_uint(fk[nodeL * 17 + k]);
      float wg = wk[nodeL * 17 + k];
      const uint4 hv = ((const uint4*)(hg + (size_t)(u & 1023u) * FLR))[q];
      u32 p[4] = {hv.x, hv.y, hv.z, hv.w};
#pragma unroll
      for (int d = 0; d < 4; ++d) {
        float lo = __uint_as_float(p[d] << 16) * wg;
        float hi = __uint_as_float(p[d] & 0xFFFF0000u) * wg;
        m[2 * d]     += lo;  xx[2 * d]     = fmaxf(xx[2 * d], lo);
        m[2 * d + 1] += hi;  xx[2 * d + 1] = fmaxf(xx[2 * d + 1], hi);
      }
    }

    uint4 om, ox;
    om.x = pack2(m[0] * 0.0625f, m[1] * 0.0625f);
    om.y = pack2(m[2] * 0.0625f, m[3] * 0.0625f);
    om.z = pack2(m[4] * 0.0625f, m[5] * 0.0625f);
    om.w = pack2(m[6] * 0.0625f, m[7] * 0.0625f);
    ox.x = pack2(xx[0], xx[1]); ox.y = pack2(xx[2], xx[3]);
    ox.z = pack2(xx[4], xx[5]); ox.w = pack2(xx[6], xx[7]);
    *(uint4*)(&agg_lds[nodeL * 136 + q * 8])       = om;
    *(uint4*)(&agg_lds[nodeL * 136 + FLR + q * 8]) = ox;
  }
  __syncthreads();

  const int mt  = w & 3;
  const int ntb = (w >> 2) * 4;
  const int rowL = mt * 16 + (lane & 15);
  const int grow = g * L + nb0 + rowL;
  const int kq = (lane >> 4) * 8;

  f32x4 acc[4];
#pragma unroll
  for (int nt = 0; nt < 4; ++nt) acc[nt] = f32x4{0.f, 0.f, 0.f, 0.f};

  const float* xr = x + (size_t)grow * IN;
  const bf16x8* __restrict__ bp = (const bf16x8*)Bp;
  const int tileA = (g * 16 + blockIdx.x) * 4 + mt;

#pragma unroll
  for (int ks = 0; ks < 8; ++ks) {
    bf16x8 a;
    if (ks < 4) {
      if (xbf) {
        a = *(const bf16x8*)(xbf + (((size_t)tileA * 4 + ks) * 64 + lane) * 8);
      } else {
        float4 xa = *(const float4*)(xr + ks * 32 + kq);
        float4 xb = *(const float4*)(xr + ks * 32 + kq + 4);
        union { __hip_bfloat162 h2[4]; bf16x8 v; } cv;
        cv.h2[0] = __float22bfloat162_rn(float2{xa.x, xa.y});
        cv.h2[1] = __float22bfloat162_rn(float2{xa.z, xa.w});
        cv.h2[2] = __float22bfloat162_rn(float2{xb.x, xb.y});
        cv.h2[3] = __float22bfloat162_rn(float2{xb.z, xb.w});
        a = cv.v;
      }
    } else {
      a = *(const bf16x8*)(&agg_lds[rowL * 136 + (ks - 4) * 32 + kq]);
    }
#pragma unroll
    for (int nt = 0; nt < 4; ++nt) {
      bf16x8 bb = bp[((ntb + nt) * 8 + ks) * 64 + lane];
      acc[nt] = __builtin_amdgcn_mfma_f32_16x16x32_bf16(a, bb, acc[nt], 0, 0, 0);
    }
  }

  const int rbase = (lane >> 4) * 4;
  const int col = lane & 15;
  const int mrow = g * L + nb0 + mt * 16;
#pragma unroll
  for (int nt = 0; nt < 4; ++nt) {
    float bias = bout[(ntb + nt) * 16 + col];
#pragma unroll
    for (int r = 0; r < 4; ++r) {
      float v = acc[nt][r] + bias;
      out[(size_t)(mrow + rbase + r) * OUT + (ntb + nt) * 16 + col] = fmaxf(v, 0.0f);
    }
  }
}

// ---------------------------------------------------------------------------
// k_abl<MODE> — DIAGNOSTIC ABLATIONS (this round only). Cumulative phases of
// k_fused, writing NOTHING to global memory; results kept live against DCE
// with asm volatile (guide rule #17). Each appears as its own rocprof row:
//   MODE 0: distance+key compute only          -> dist/load cost
//   MODE 1: + fmed3 ladder + level-1 LDS store -> ladder = M1 - M0
//   MODE 2: + merge tree + fk/wk               -> merge  = M2 - M1
//   MODE 3: + aggregation gather               -> agg    = M3 - M2
// GEMM cost ≈ k_fused - M3.
// ---------------------------------------------------------------------------
template<int MODE>
__global__ __launch_bounds__(512) void k_abl(
    const float* __restrict__ s_buf, const u16* __restrict__ h_buf)
{
  __shared__ alignas(16) float lists[8 * 64 * 17];
  __shared__ float fk[64 * 17];
  u16* agg_lds = (u16*)lists;
  float* wk = lists + 4608;

  const int lane = threadIdx.x & 63;
  const int w = __builtin_amdgcn_readfirstlane(threadIdx.x >> 6);
  const int g = blockIdx.y;
  const int nb0 = blockIdx.x * 64;
  const int node = g * L + nb0 + lane;

  const float4 si = *(const float4*)(s_buf + (size_t)node * 4);
  const float4* __restrict__ sg = (const float4*)(s_buf + (size_t)g * L * 4);
  const int jb = __builtin_amdgcn_readfirstlane(w * 128);

  float b[16];
#pragma unroll
  for (int k = 0; k < 16; ++k) b[k] = 3.0e38f;

#pragma unroll 4
  for (int j = 0; j < 128; ++j) {
    float4 sj = sg[jb + j];
    float dx = si.x - sj.x, dy = si.y - sj.y;
    float dz = si.z - sj.z, dw2 = si.w - sj.w;
    float d2 = fmaf(dw2, dw2, fmaf(dz, dz, fmaf(dy, dy, dx * dx)));
    u32 db = __float_as_uint(d2);
    float key = __uint_as_float((db & 0xFFFFFC00u) | (u32)(jb + j));
    if constexpr (MODE == 0) {
      asm volatile("" : : "v"(key));          // keep dist path live, no ladder
    } else {
#pragma unroll
      for (int k = 15; k >= 1; --k) b[k] = __builtin_amdgcn_fmed3f(key, b[k - 1], b[k]);
      b[0] = fminf(key, b[0]);
    }
  }

  if constexpr (MODE == 0) return;

#pragma unroll
  for (int k = 0; k < 16; ++k) lists[(w * 64 + lane) * 17 + k] = b[k];
  __syncthreads();

  if constexpr (MODE == 1) {
    float v = lists[((threadIdx.x * 29) & 4095) * 2 + 1 - 1];  // touch LDS
    asm volatile("" : : "v"(v));
    return;
  } else {
    float c[16];
    if (w < 4) {
#pragma unroll
      for (int i = 0; i < 16; ++i)
        c[i] = fminf(b[i], lists[((w + 4) * 64 + lane) * 17 + (15 - i)]);
#pragma unroll
      for (int dd = 8; dd >= 1; dd >>= 1) {
#pragma unroll
        for (int i = 0; i < 16; ++i) {
          if ((i & dd) == 0) {
            float lo = fminf(c[i], c[i | dd]);
            float hi = fmaxf(c[i], c[i | dd]);
            c[i] = lo; c[i | dd] = hi;
          }
        }
      }
#pragma unroll
      for (int k = 0; k < 16; ++k) lists[(w * 64 + lane) * 17 + k] = c[k];
    }
    __syncthreads();
    if (w < 2) {
#pragma unroll
      for (int i = 0; i < 16; ++i)
        c[i] = fminf(c[i], lists[((w + 2) * 64 + lane) * 17 + (15 - i)]);
#pragma unroll
      for (int dd = 8; dd >= 1; dd >>= 1) {
#pragma unroll
        for (int i = 0; i < 16; ++i) {
          if ((i & dd) == 0) {
            float lo = fminf(c[i], c[i | dd]);
            float hi = fmaxf(c[i], c[i | dd]);
            c[i] = lo; c[i | dd] = hi;
          }
        }
      }
#pragma unroll
      for (int k = 0; k < 16; ++k) lists[(w * 64 + lane) * 17 + k] = c[k];
    }
    __syncthreads();
    if (w == 0) {
#pragma unroll
      for (int i = 0; i < 16; ++i) {
        float o = lists[(64 + lane) * 17 + (15 - i)];
        float kf = fminf(c[i], o);
        fk[lane * 17 + i] = kf;
        wk[lane * 17 + i] =
            __expf(-10.0f * __uint_as_float(__float_as_uint(kf) & 0xFFFFFC00u));
      }
    }
    __syncthreads();

    if constexpr (MODE == 2) {
      float v1 = fk[(threadIdx.x * 17) & 1023];
      float v2 = wk[(threadIdx.x * 13) & 1023];
      asm volatile("" : : "v"(v1), "v"(v2));
      return;
    } else {
      // ---- aggregation (MODE 3)
      const int q     = lane & 7;
      const int nodeL = w * 8 + (lane >> 3);
      const u16* __restrict__ hg = h_buf + (size_t)g * L * FLR;

      float m[8], xx[8];
#pragma unroll
      for (int j = 0; j < 8; ++j) { m[j] = 0.f; xx[j] = -3.0e38f; }

#pragma unroll 4
      for (int k = 0; k < 16; ++k) {
        u32 u    = __float_as_uint(fk[nodeL * 17 + k]);
        float wg = wk[nodeL * 17 + k];
        const uint4 hv = ((const uint4*)(hg + (size_t)(u & 1023u) * FLR))[q];
        u32 p[4] = {hv.x, hv.y, hv.z, hv.w};
#pragma unroll
        for (int d = 0; d < 4; ++d) {
          float lo = __uint_as_float(p[d] << 16) * wg;
          float hi = __uint_as_float(p[d] & 0xFFFF0000u) * wg;
          m[2 * d]     += lo;  xx[2 * d]     = fmaxf(xx[2 * d], lo);
          m[2 * d + 1] += hi;  xx[2 * d + 1] = fmaxf(xx[2 * d + 1], hi);
        }
      }

      uint4 om, ox;
      om.x = pack2(m[0] * 0.0625f, m[1] * 0.0625f);
      om.y = pack2(m[2] * 0.0625f, m[3] * 0.0625f);
      om.z = pack2(m[4] * 0.0625f, m[5] * 0.0625f);
      om.w = pack2(m[6] * 0.0625f, m[7] * 0.0625f);
      ox.x = pack2(xx[0], xx[1]); ox.y = pack2(xx[2], xx[3]);
      ox.z = pack2(xx[4], xx[5]); ox.w = pack2(xx[6], xx[7]);
      *(uint4*)(&agg_lds[nodeL * 136 + q * 8])       = om;
      *(uint4*)(&agg_lds[nodeL * 136 + FLR + q * 8]) = ox;
      __syncthreads();
      uint4 t = *(uint4*)(&agg_lds[(threadIdx.x * 16) & 8191]);
      asm volatile("" : : "v"(t.x), "v"(t.y), "v"(t.z), "v"(t.w));
    }
  }
}

extern "C" void kernel_launch(void* const* d_in, const int* in_sizes, int n_in,
                              void* d_out, int out_size, void* d_ws, size_t ws_size,
                              hipStream_t stream) {
  const float* x    = (const float*)d_in[0];
  const float* Ws   = (const float*)d_in[1];
  const float* bs   = (const float*)d_in[2];
  const float* Wh   = (const float*)d_in[3];
  const float* bh   = (const float*)d_in[4];
  const float* Wout = (const float*)d_in[5];
  const float* bout = (const float*)d_in[6];
  float* out = (float*)d_out;

  char* ws = (char*)d_ws;
  float* s_buf = (float*)ws;                                      // 1 MiB
  u16*   h_buf = (u16*)(ws + (1 << 20));                          // 8 MiB
  u16*   Bp    = (u16*)(ws + (1 << 20) + (8 << 20));              // 64 KiB
  u16*   Whp   = (u16*)(ws + (1 << 20) + (8 << 20) + (64 << 10)); // 16 KiB
  u16*   xbf   = (ws_size >= (26u << 20)) ? (u16*)(ws + (10 << 20)) : nullptr;

  k_pack<<<17, 256, 0, stream>>>(Wout, Wh, Bp, Whp);
  k_sh<<<N / 64, 256, 0, stream>>>(x, Ws, bs, Whp, bh, s_buf, h_buf, xbf);
  dim3 gknn(L / 64, Bb);
  k_fused<<<gknn, 512, 0, stream>>>(s_buf, h_buf, x, Bp, xbf, bout, out);

  // ---- DIAGNOSTIC (this round only): phase-cumulative ablations, no output
  k_abl<0><<<gknn, 512, 0, stream>>>(s_buf, h_buf);
  k_abl<1><<<gknn, 512, 0, stream>>>(s_buf, h_buf);
  k_abl<2><<<gknn, 512, 0, stream>>>(s_buf, h_buf);
  k_abl<3><<<gknn, 512, 0, stream>>>(s_buf, h_buf);
}

// Round 7
// 162.425 us; speedup vs baseline: 1.8984x; 1.8984x over previous
//
#include <hip/hip_runtime.h>
#include <hip/hip_bf16.h>

using u16 = unsigned short;
using u32 = unsigned int;

typedef __bf16 bf16x8 __attribute__((ext_vector_type(8)));
typedef float f32x4 __attribute__((ext_vector_type(4)));

__device__ __forceinline__ u16 f2bf(float f) {
  union { float f; u32 u; } c; c.f = f;
  u32 u = c.u;
  u32 r = u + 0x7fffu + ((u >> 16) & 1u);   // RNE
  return (u16)(r >> 16);
}
__device__ __forceinline__ float bf2f(u16 h) {
  return __uint_as_float((u32)h << 16);
}
__device__ __forceinline__ u32 pack2(float a, float b) {
  return (u32)f2bf(a) | ((u32)f2bf(b) << 16);
}
// split v into bf16 hi + bf16 lo (v ~= hi + lo, error ~2^-18 |v|)
__device__ __forceinline__ void bsplit(float v, u16& hi, u16& lo) {
  hi = f2bf(v);
  lo = f2bf(v - bf2f(hi));
}

constexpr int Bb  = 64;    // graphs
constexpr int L   = 1024;  // nodes/graph
constexpr int IN  = 128;
constexpr int OUT = 128;
constexpr int FLR = 64;
constexpr int N   = Bb * L;

// ---------------------------------------------------------------------------
// k_pack: one-time weight repack into MFMA B-fragment order (bf16). UNCHANGED.
// ---------------------------------------------------------------------------
__global__ __launch_bounds__(256) void k_pack(
    const float* __restrict__ Wout, const float* __restrict__ Wh,
    u16* __restrict__ Bp, u16* __restrict__ Whp)
{
  const int blk = blockIdx.x;
  if (blk < 16) {
    int t2 = blk * 256 + threadIdx.x;    // 0..4095 frag-lanes
    int lane = t2 & 63, kstep = (t2 >> 6) & 7, ntile = t2 >> 9;
    int n  = ntile * 16 + (lane & 15);
    int kb = kstep * 32 + (lane >> 4) * 8;
    u16* dst = Bp + (size_t)t2 * 8;
#pragma unroll
    for (int j = 0; j < 8; ++j) dst[j] = f2bf(Wout[(kb + j) * OUT + n]);
  } else {
#pragma unroll
    for (int i = 0; i < 4; ++i) {
      int t2 = i * 256 + threadIdx.x;    // 0..1023 frag-lanes
      int l = t2 & 63, ks = (t2 >> 6) & 3, nt = t2 >> 8;
      int kb = ks * 32 + (l >> 4) * 8;
      u16* dst = Whp + (size_t)t2 * 8;
#pragma unroll
      for (int j = 0; j < 8; ++j)
        dst[j] = f2bf(Wh[(size_t)(kb + j) * FLR + nt * 16 + (l & 15)]);
    }
  }
}

// ---------------------------------------------------------------------------
// k_sh: UNCHANGED from round 5 (passing).
// ---------------------------------------------------------------------------
__global__ __launch_bounds__(256) void k_sh(
    const float* __restrict__ x, const float* __restrict__ Ws, const float* __restrict__ bs,
    const u16* __restrict__ Whp, const float* __restrict__ bh,
    float* __restrict__ s_buf, u16* __restrict__ h_buf, u16* __restrict__ xbf)
{
  __shared__ alignas(16) u16 whl[128 * 64];   // 16 KB: Wh bf16 frags

  const int tid = threadIdx.x;
  {
    const uint4* __restrict__ src = (const uint4*)Whp;
    uint4* dstl = (uint4*)whl;
#pragma unroll
    for (int i = 0; i < 4; ++i) {
      int idx = i * 256 + tid;
      dstl[idx] = src[idx];
    }
  }

  const int blk = blockIdx.x;
  const int lane = tid & 63;
  const int w = __builtin_amdgcn_readfirstlane(tid >> 6);
  const int mb = blk * 64 + w * 16;        // m-tile base node
  const int col = lane & 15;
  const int kq  = lane >> 4;               // 0..3
  const int mrow = mb + col;               // this lane's A row

  const float* xr = x + (size_t)mrow * IN;

  float sp0 = 0.f, sp1 = 0.f, sp2 = 0.f, sp3 = 0.f;
  bf16x8 a[4];
#pragma unroll
  for (int ks = 0; ks < 4; ++ks) {
    float4 xa = *(const float4*)(xr + ks * 32 + kq * 8);
    float4 xb = *(const float4*)(xr + ks * 32 + kq * 8 + 4);
    float xf[8] = {xa.x, xa.y, xa.z, xa.w, xb.x, xb.y, xb.z, xb.w};
#pragma unroll
    for (int j = 0; j < 8; ++j) {
      const float4 wsr = *(const float4*)(Ws + (size_t)(ks * 32 + kq * 8 + j) * 4);
      sp0 = fmaf(xf[j], wsr.x, sp0);
      sp1 = fmaf(xf[j], wsr.y, sp1);
      sp2 = fmaf(xf[j], wsr.z, sp2);
      sp3 = fmaf(xf[j], wsr.w, sp3);
    }
    union { __hip_bfloat162 h2[4]; bf16x8 v; } cv;
    cv.h2[0] = __float22bfloat162_rn(float2{xf[0], xf[1]});
    cv.h2[1] = __float22bfloat162_rn(float2{xf[2], xf[3]});
    cv.h2[2] = __float22bfloat162_rn(float2{xf[4], xf[5]});
    cv.h2[3] = __float22bfloat162_rn(float2{xf[6], xf[7]});
    a[ks] = cv.v;
  }

  if (xbf) {
#pragma unroll
    for (int ks = 0; ks < 4; ++ks)
      *(bf16x8*)(xbf + (((size_t)(blk * 4 + w) * 4 + ks) * 64 + lane) * 8) = a[ks];
  }

  sp0 += __shfl_xor(sp0, 16, 64); sp0 += __shfl_xor(sp0, 32, 64);
  sp1 += __shfl_xor(sp1, 16, 64); sp1 += __shfl_xor(sp1, 32, 64);
  sp2 += __shfl_xor(sp2, 16, 64); sp2 += __shfl_xor(sp2, 32, 64);
  sp3 += __shfl_xor(sp3, 16, 64); sp3 += __shfl_xor(sp3, 32, 64);
  if (kq == 0) {
    float4 sv;
    sv.x = sp0 + bs[0]; sv.y = sp1 + bs[1];
    sv.z = sp2 + bs[2]; sv.w = sp3 + bs[3];
    *(float4*)(s_buf + (size_t)mrow * 4) = sv;
  }

  __syncthreads();   // whl ready

  f32x4 acc[4];
#pragma unroll
  for (int nt = 0; nt < 4; ++nt) acc[nt] = f32x4{0.f, 0.f, 0.f, 0.f};

  const bf16x8* __restrict__ wf = (const bf16x8*)whl;
#pragma unroll
  for (int nt = 0; nt < 4; ++nt) {
#pragma unroll
    for (int ks = 0; ks < 4; ++ks) {
      acc[nt] = __builtin_amdgcn_mfma_f32_16x16x32_bf16(
          a[ks], wf[(nt * 4 + ks) * 64 + lane], acc[nt], 0, 0, 0);
    }
  }

#pragma unroll
  for (int nt = 0; nt < 4; ++nt) {
    float bias = bh[nt * 16 + col];
#pragma unroll
    for (int r = 0; r < 4; ++r) {
      float v = acc[nt][r] + bias;
      h_buf[(size_t)(mb + kq * 4 + r) * FLR + nt * 16 + col] = f2bf(v);
    }
  }
}

// ---------------------------------------------------------------------------
// k_fused — ROUND 7: distances moved to the matrix pipe.
// d2(i,j) = sq_i + sq_j - 2 si.sj is computed by TWO mfma_16x16x32_bf16 per
// 16q x 16c tile with split-bf16 operands folded into the K dimension:
//   A row j (LDS-packed): k0-3 = sj_hi, k4-7 = sj_lo, k8 = sqj_hi,
//                         k9 = sqj_lo, k10 = k11 = 1.0, k12-15 = 0
//   B1 col i: k0-3 = -2*si_hi, k4-7 = -2*si_hi, k8 = k9 = 1.0,
//             k10 = sqi_hi, k11 = sqi_lo   (rest 0)
//   B2 col i: k0-3 = -2*si_lo              (rest 0)
//   acc = mfma(A,B1, mfma(A,B2,0)) = sq_i + sq_j - 2 si.sj  (lo*lo dropped,
//   |err| <= ~3e-5 ~= the key-truncation granularity already tolerated).
// C layout (verified): col = lane&15 = query, row = kq*4+r = candidate.
// Per-candidate VALU drops 27 -> ~18 (key OR + exact fp32 fmed3 ladder only).
// Wave w covers query-tile qt=w&3, candidate-half ch=w>>2; the partial list
// of (ch,kq) lands in lists[src=ch*4+kq][node] so the merge tree, fk/wk, agg
// and output GEMM are UNCHANGED (stage-1 merge now reads both sides from LDS).
// A-pack (32 KB) aliases the lists region; barriers separate the phases.
// ---------------------------------------------------------------------------
__global__ __launch_bounds__(512) void k_fused(
    const float* __restrict__ s_buf, const u16* __restrict__ h_buf,
    const float* __restrict__ x, const u16* __restrict__ Bp,
    const u16* __restrict__ xbf,
    const float* __restrict__ bout, float* __restrict__ out)
{
  __shared__ alignas(16) float lists[8 * 64 * 17];   // 8704 floats (34816 B)
  __shared__ float fk[64 * 17];                      // final 16 keys per node
  u16* agg_lds = (u16*)lists;          // [64][136] bf16, bytes [0, 17408)
  u16* apack   = (u16*)lists;          // [1024][16] bf16 A-rows, bytes [0, 32768)
  float* wk = lists + 4608;            // [64*17] f32 weights (dead region at write)

  const int lane = threadIdx.x & 63;
  const int w = __builtin_amdgcn_readfirstlane(threadIdx.x >> 6);
  const int g = blockIdx.y;
  const int nb0 = blockIdx.x * 64;

  // ---- phase A: pack this graph's 1024 candidate rows into LDS (2/thread)
  {
    const float4* __restrict__ sgf = (const float4*)(s_buf + (size_t)g * L * 4);
#pragma unroll
    for (int i = 0; i < 2; ++i) {
      int c = threadIdx.x + i * 512;
      float4 s = sgf[c];
      float sq = fmaf(s.w, s.w, fmaf(s.z, s.z, fmaf(s.y, s.y, s.x * s.x)));
      u16 xh,xl,yh,yl,zh,zl,wh,wl,qh,ql;
      bsplit(s.x, xh, xl); bsplit(s.y, yh, yl);
      bsplit(s.z, zh, zl); bsplit(s.w, wh, wl);
      bsplit(sq,  qh, ql);
      union { u16 r[16]; uint4 v[2]; } ru;
      ru.r[0]=xh; ru.r[1]=yh; ru.r[2]=zh;  ru.r[3]=wh;
      ru.r[4]=xl; ru.r[5]=yl; ru.r[6]=zl;  ru.r[7]=wl;
      ru.r[8]=qh; ru.r[9]=ql; ru.r[10]=0x3F80u; ru.r[11]=0x3F80u;
      ru.r[12]=0; ru.r[13]=0; ru.r[14]=0;  ru.r[15]=0;
      *(uint4*)(apack + c * 16)     = ru.v[0];
      *(uint4*)(apack + c * 16 + 8) = ru.v[1];
    }
  }

  // ---- phase B: per-lane query B-fragments (registers)
  const int col = lane & 15;
  const int kq  = lane >> 4;
  const int qt  = w & 3;                  // query tile (16 nodes)
  const int ch  = w >> 2;                 // candidate half (512 cands)
  const int nodeL = qt * 16 + col;        // this lane's query node (0..63)

  union { u16 r[8]; bf16x8 v; } b1u, b2u;
#pragma unroll
  for (int i = 0; i < 8; ++i) { b1u.r[i] = 0; b2u.r[i] = 0; }
  {
    float4 si = *(const float4*)(s_buf + (size_t)(g * L + nb0 + nodeL) * 4);
    float sqi = fmaf(si.w, si.w, fmaf(si.z, si.z, fmaf(si.y, si.y, si.x * si.x)));
    u16 xh,xl,yh,yl,zh,zl,wh,wl,qh,ql;
    bsplit(si.x, xh, xl); bsplit(si.y, yh, yl);
    bsplit(si.z, zh, zl); bsplit(si.w, wh, wl);
    bsplit(sqi,  qh, ql);
    if (kq == 0) {
      b1u.r[0] = f2bf(-2.0f * bf2f(xh)); b1u.r[1] = f2bf(-2.0f * bf2f(yh));
      b1u.r[2] = f2bf(-2.0f * bf2f(zh)); b1u.r[3] = f2bf(-2.0f * bf2f(wh));
      b1u.r[4] = b1u.r[0]; b1u.r[5] = b1u.r[1];
      b1u.r[6] = b1u.r[2]; b1u.r[7] = b1u.r[3];
      b2u.r[0] = f2bf(-2.0f * bf2f(xl)); b2u.r[1] = f2bf(-2.0f * bf2f(yl));
      b2u.r[2] = f2bf(-2.0f * bf2f(zl)); b2u.r[3] = f2bf(-2.0f * bf2f(wl));
    } else if (kq == 1) {
      b1u.r[0] = 0x3F80u; b1u.r[1] = 0x3F80u;   // pair with A's sqj_hi/lo
      b1u.r[2] = qh;      b1u.r[3] = ql;        // sqi via A's 1.0 slots
    }
  }

  __syncthreads();   // apack ready

  // ---- phase 1: 32 tiles x (1 ds_read + 2 MFMA + 4 keys + 4x16 ladder)
  float b[16];
#pragma unroll
  for (int k = 0; k < 16; ++k) b[k] = 3.0e38f;

  union { u16 r[8]; bf16x8 v; } zu;
#pragma unroll
  for (int i = 0; i < 8; ++i) zu.r[i] = 0;

  const int cbase0 = ch * 512;
#pragma unroll 4
  for (int tc = 0; tc < 32; ++tc) {
    const int cb = cbase0 + tc * 16;
    bf16x8 av = zu.v;
    if (kq < 2) av = *(const bf16x8*)(apack + (cb + col) * 16 + kq * 8);
    f32x4 acc = __builtin_amdgcn_mfma_f32_16x16x32_bf16(av, b2u.v,
                    f32x4{0.f, 0.f, 0.f, 0.f}, 0, 0, 0);
    acc = __builtin_amdgcn_mfma_f32_16x16x32_bf16(av, b1u.v, acc, 0, 0, 0);
#pragma unroll
    for (int r = 0; r < 4; ++r) {
      u32 db = __float_as_uint(acc[r]);
      float key = __uint_as_float((db & 0xFFFFFC00u) | (u32)(cb + kq * 4 + r));
#pragma unroll
      for (int k = 15; k >= 1; --k) b[k] = __builtin_amdgcn_fmed3f(key, b[k - 1], b[k]);
      b[0] = fminf(key, b[0]);
    }
  }

  __syncthreads();   // all apack reads done before lists overwrite

  // ---- dump partial lists: slot (src, node)
  {
    const int src = ch * 4 + kq;
#pragma unroll
    for (int k = 0; k < 16; ++k) lists[(src * 64 + nodeL) * 17 + k] = b[k];
  }
  __syncthreads();

  // ---- merge tree (stage 1 reads both operands from LDS; rest unchanged)
  float c[16];
  if (w < 4) {
#pragma unroll
    for (int i = 0; i < 16; ++i)
      c[i] = fminf(lists[(w * 64 + lane) * 17 + i],
                   lists[((w + 4) * 64 + lane) * 17 + (15 - i)]);
#pragma unroll
    for (int dd = 8; dd >= 1; dd >>= 1) {
#pragma unroll
      for (int i = 0; i < 16; ++i) {
        if ((i & dd) == 0) {
          float lo = fminf(c[i], c[i | dd]);
          float hi = fmaxf(c[i], c[i | dd]);
          c[i] = lo; c[i | dd] = hi;
        }
      }
    }
#pragma unroll
    for (int k = 0; k < 16; ++k) lists[(w * 64 + lane) * 17 + k] = c[k];
  }
  __syncthreads();
  if (w < 2) {
#pragma unroll
    for (int i = 0; i < 16; ++i)
      c[i] = fminf(c[i], lists[((w + 2) * 64 + lane) * 17 + (15 - i)]);
#pragma unroll
    for (int dd = 8; dd >= 1; dd >>= 1) {
#pragma unroll
      for (int i = 0; i < 16; ++i) {
        if ((i & dd) == 0) {
          float lo = fminf(c[i], c[i | dd]);
          float hi = fmaxf(c[i], c[i | dd]);
          c[i] = lo; c[i | dd] = hi;
        }
      }
    }
#pragma unroll
    for (int k = 0; k < 16; ++k) lists[(w * 64 + lane) * 17 + k] = c[k];
  }
  __syncthreads();
  if (w == 0) {
#pragma unroll
    for (int i = 0; i < 16; ++i) {
      float o = lists[(64 + lane) * 17 + (15 - i)];
      float kf = fminf(c[i], o);
      fk[lane * 17 + i] = kf;
      wk[lane * 17 + i] =
          __expf(-10.0f * __uint_as_float(__float_as_uint(kf) & 0xFFFFFC00u));
    }
  }
  __syncthreads();        // fk/wk ready; lists[] selection data dead

  // ---- aggregation: lane <-> (node, 8-dim chunk); no shuffles (unchanged)
  {
    const int q     = lane & 7;              // dim chunk (8 bf16 = 16 B)
    const int nodeA = w * 8 + (lane >> 3);   // 0..63
    const u16* __restrict__ hg = h_buf + (size_t)g * L * FLR;

    float m[8], xx[8];
#pragma unroll
    for (int j = 0; j < 8; ++j) { m[j] = 0.f; xx[j] = -3.0e38f; }

#pragma unroll 4
    for (int k = 0; k < 16; ++k) {
      u32 u    = __float_as_uint(fk[nodeA * 17 + k]);
      float wg = wk[nodeA * 17 + k];
      const uint4 hv = ((const uint4*)(hg + (size_t)(u & 1023u) * FLR))[q];
      u32 p[4] = {hv.x, hv.y, hv.z, hv.w};
#pragma unroll
      for (int d = 0; d < 4; ++d) {
        float lo = __uint_as_float(p[d] << 16) * wg;
        float hi = __uint_as_float(p[d] & 0xFFFF0000u) * wg;
        m[2 * d]     += lo;  xx[2 * d]     = fmaxf(xx[2 * d], lo);
        m[2 * d + 1] += hi;  xx[2 * d + 1] = fmaxf(xx[2 * d + 1], hi);
      }
    }

    uint4 om, ox;
    om.x = pack2(m[0] * 0.0625f, m[1] * 0.0625f);
    om.y = pack2(m[2] * 0.0625f, m[3] * 0.0625f);
    om.z = pack2(m[4] * 0.0625f, m[5] * 0.0625f);
    om.w = pack2(m[6] * 0.0625f, m[7] * 0.0625f);
    ox.x = pack2(xx[0], xx[1]); ox.y = pack2(xx[2], xx[3]);
    ox.z = pack2(xx[4], xx[5]); ox.w = pack2(xx[6], xx[7]);
    *(uint4*)(&agg_lds[nodeA * 136 + q * 8])       = om;
    *(uint4*)(&agg_lds[nodeA * 136 + FLR + q * 8]) = ox;
  }
  __syncthreads();

  // ---- output GEMM (unchanged)
  const int mt  = w & 3;
  const int ntb = (w >> 2) * 4;
  const int rowL = mt * 16 + (lane & 15);
  const int grow = g * L + nb0 + rowL;
  const int kq8 = (lane >> 4) * 8;

  f32x4 acc[4];
#pragma unroll
  for (int nt = 0; nt < 4; ++nt) acc[nt] = f32x4{0.f, 0.f, 0.f, 0.f};

  const float* xr = x + (size_t)grow * IN;
  const bf16x8* __restrict__ bp = (const bf16x8*)Bp;
  const int tileA = (g * 16 + blockIdx.x) * 4 + mt;

#pragma unroll
  for (int ks = 0; ks < 8; ++ks) {
    bf16x8 a;
    if (ks < 4) {
      if (xbf) {
        a = *(const bf16x8*)(xbf + (((size_t)tileA * 4 + ks) * 64 + lane) * 8);
      } else {
        float4 xa = *(const float4*)(xr + ks * 32 + kq8);
        float4 xb = *(const float4*)(xr + ks * 32 + kq8 + 4);
        union { __hip_bfloat162 h2[4]; bf16x8 v; } cv;
        cv.h2[0] = __float22bfloat162_rn(float2{xa.x, xa.y});
        cv.h2[1] = __float22bfloat162_rn(float2{xa.z, xa.w});
        cv.h2[2] = __float22bfloat162_rn(float2{xb.x, xb.y});
        cv.h2[3] = __float22bfloat162_rn(float2{xb.z, xb.w});
        a = cv.v;
      }
    } else {
      a = *(const bf16x8*)(&agg_lds[rowL * 136 + (ks - 4) * 32 + kq8]);
    }
#pragma unroll
    for (int nt = 0; nt < 4; ++nt) {
      bf16x8 bb = bp[((ntb + nt) * 8 + ks) * 64 + lane];
      acc[nt] = __builtin_amdgcn_mfma_f32_16x16x32_bf16(a, bb, acc[nt], 0, 0, 0);
    }
  }

  const int rbase = (lane >> 4) * 4;
  const int colO = lane & 15;
  const int mrow = g * L + nb0 + mt * 16;
#pragma unroll
  for (int nt = 0; nt < 4; ++nt) {
    float bias = bout[(ntb + nt) * 16 + colO];
#pragma unroll
    for (int r = 0; r < 4; ++r) {
      float v = acc[nt][r] + bias;
      out[(size_t)(mrow + rbase + r) * OUT + (ntb + nt) * 16 + colO] = fmaxf(v, 0.0f);
    }
  }
}

extern "C" void kernel_launch(void* const* d_in, const int* in_sizes, int n_in,
                              void* d_out, int out_size, void* d_ws, size_t ws_size,
                              hipStream_t stream) {
  const float* x    = (const float*)d_in[0];
  const float* Ws   = (const float*)d_in[1];
  const float* bs   = (const float*)d_in[2];
  const float* Wh   = (const float*)d_in[3];
  const float* bh   = (const float*)d_in[4];
  const float* Wout = (const float*)d_in[5];
  const float* bout = (const float*)d_in[6];
  float* out = (float*)d_out;

  char* ws = (char*)d_ws;
  float* s_buf = (float*)ws;                                      // 1 MiB
  u16*   h_buf = (u16*)(ws + (1 << 20));                          // 8 MiB
  u16*   Bp    = (u16*)(ws + (1 << 20) + (8 << 20));              // 64 KiB
  u16*   Whp   = (u16*)(ws + (1 << 20) + (8 << 20) + (64 << 10)); // 16 KiB
  u16*   xbf   = (ws_size >= (26u << 20)) ? (u16*)(ws + (10 << 20)) : nullptr;

  k_pack<<<17, 256, 0, stream>>>(Wout, Wh, Bp, Whp);
  k_sh<<<N / 64, 256, 0, stream>>>(x, Ws, bs, Whp, bh, s_buf, h_buf, xbf);
  dim3 gknn(L / 64, Bb);
  k_fused<<<gknn, 512, 0, stream>>>(s_buf, h_buf, x, Bp, xbf, bout, out);
}